// Round 2
// baseline (456.175 us; speedup 1.0000x reference)
//
#include <hip/hip_runtime.h>

#define DEVINL __device__ __forceinline__

typedef unsigned short u16;
typedef unsigned long long u64;
typedef __attribute__((ext_vector_type(8))) short bf16x8;   // 8 bf16 = 4 VGPRs
typedef __attribute__((ext_vector_type(16))) float f32x16;  // 32x32 C/D frag

// problem sizes
#define NB   65536
#define OBSD 128
#define ED   64
#define HD_  128
#define NT   7
#define NA   16

// bf16 weight workspace layout (elements)
#define OFF_W1   0        // 64x128
#define OFF_W2   8192     // 64x64
#define OFF_WP   12288    // 64x128
#define OFF_INP  20480    // 192x64 (Wq rows 0..63, Wk 64..127, Wv 128..191)
#define OFF_OUTP 32768    // 64x64
#define OFF_WIH  36864    // 384x128
#define OFF_WHH  86016    // 384x128
#define OFF_POL  135168   // 16x128
#define W_TOTAL  137216

DEVINL u16 f2bf(float f) {                 // RNE f32 -> bf16 (finite inputs)
  unsigned u = __float_as_uint(f);
  u += 0x7fff + ((u >> 16) & 1);
  return (u16)(u >> 16);
}
DEVINL float bf2f(u16 h) { return __uint_as_float(((unsigned)h) << 16); }

DEVINL f32x16 mfma(bf16x8 a, bf16x8 b, f32x16 c) {
  return __builtin_amdgcn_mfma_f32_32x32x16_bf16(a, b, c, 0, 0, 0);
}
DEVINL f32x16 zero16() {
  f32x16 z;
#pragma unroll
  for (int i = 0; i < 16; ++i) z[i] = 0.f;
  return z;
}

// A-frag from LDS: 16B as two 8B reads (rows are 8B- but not 16B-aligned)
DEVINL bf16x8 ldsA(const u16* p) {
  union { bf16x8 v; u64 u[2]; } t;
  t.u[0] = *(const u64*)p;
  t.u[1] = *(const u64*)(p + 4);
  return t.v;
}

// one 32x32 C tile: A[aRow, k] (LDS, stride S) @ W[n=lane&31 row][k] (global bf16)
template<int KS>
DEVINL f32x16 gemm_acc(const u16* __restrict__ bufA, int S, int aRow, int khalf,
                       const u16* __restrict__ wRow, f32x16 acc) {
  const u16* ap = bufA + aRow * S + khalf;
  const u16* bp = wRow + khalf;
#pragma unroll
  for (int ks = 0; ks < KS; ++ks) {
    bf16x8 a = ldsA(ap + ks * 16);
    bf16x8 b = *(const bf16x8*)(bp + ks * 16);   // 16B aligned
    acc = mfma(a, b, acc);
  }
  return acc;
}

// C-frag -> LDS bf16 with bias (+optional relu). col already includes N offset.
DEVINL void epiLDS(const f32x16& acc, float bias, int rowOff, int col,
                   u16* buf, int S, bool relu) {
#pragma unroll
  for (int r = 0; r < 16; ++r) {
    int row = rowOff + (r & 3) + 8 * (r >> 2);
    float v = acc[r] + bias;
    if (relu) v = fmaxf(v, 0.f);
    buf[row * S + col] = f2bf(v);
  }
}

DEVINL float sigf(float x) { return 1.f / (1.f + __expf(-x)); }

__global__ void pack_weights(const float* __restrict__ W1, const float* __restrict__ W2,
                             const float* __restrict__ Wp, const float* __restrict__ inpw,
                             const float* __restrict__ outpw, const float* __restrict__ wih,
                             const float* __restrict__ whh, const float* __restrict__ wpol,
                             u16* __restrict__ ws) {
  int i = blockIdx.x * 256 + threadIdx.x;
  const float* src; int off;
  if      (i < OFF_W2)  { src = W1;    off = OFF_W1; }
  else if (i < OFF_WP)  { src = W2;    off = OFF_W2; }
  else if (i < OFF_INP) { src = Wp;    off = OFF_WP; }
  else if (i < OFF_OUTP){ src = inpw;  off = OFF_INP; }
  else if (i < OFF_WIH) { src = outpw; off = OFF_OUTP; }
  else if (i < OFF_WHH) { src = wih;   off = OFF_WIH; }
  else if (i < OFF_POL) { src = whh;   off = OFF_WHH; }
  else if (i < W_TOTAL) { src = wpol;  off = OFF_POL; }
  else return;
  ws[i] = f2bf(src[i - off]);
}

__global__ __launch_bounds__(256, 2)
void aerial_main(const float* __restrict__ obs, const float* __restrict__ pb,
                 const float* __restrict__ th,
                 const float* __restrict__ b1, const float* __restrict__ b2,
                 const float* __restrict__ bp,
                 const float* __restrict__ inpb, const float* __restrict__ outpb,
                 const float* __restrict__ bih, const float* __restrict__ bhh,
                 const float* __restrict__ bpol,
                 const u16* __restrict__ wsb,
                 float* __restrict__ outLog, float* __restrict__ outBel,
                 float* __restrict__ outAttn) {
  // strides 132/68: word-stride 66/34 -> bank step 2 -> 2-way aliasing (free)
  __shared__ u16 bufP[64 * 132];   // prev_belief bf16 (persists to GRU)
  __shared__ u16 bufB[64 * 132];   // obs -> q -> teammate tile -> belief
  __shared__ u16 bufH1[64 * 68];   // t1 -> kv_in -> ctx
  __shared__ u16 bufHO[64 * 68];   // h_obs (persists to GRU)
  __shared__ u16 bufQ[64 * 68];    // q_in -> k -> v -> context

  const int tid   = threadIdx.x;
  const int lane  = tid & 63;
  const int m     = lane & 31;
  const int half  = lane >> 5;
  const int khalf = half * 8;
  const int wv    = tid >> 6;
  const int mt    = wv & 1;        // M-tile (rows 32*mt..)
  const int nh    = wv >> 1;       // N-half
  const int aRow  = 32 * mt + m;
  const int rowOff = 32 * mt + 4 * half;
  const int col64 = nh * 32 + m;   // column in 64-wide stages
  const int gRow0 = blockIdx.x * 64;

  const u16* wsW1   = wsb + OFF_W1;
  const u16* wsW2   = wsb + OFF_W2;
  const u16* wsWP   = wsb + OFF_WP;
  const u16* wsINP  = wsb + OFF_INP;
  const u16* wsOUTP = wsb + OFF_OUTP;
  const u16* wsWIH  = wsb + OFF_WIH;
  const u16* wsWHH  = wsb + OFF_WHH;
  const u16* wsPOL  = wsb + OFF_POL;

  // stage 64x128 f32 tile -> bf16 LDS (stride 132), coalesced float4
  auto stage = [&](const float* src, int srcStride, u16* dst) {
#pragma unroll
    for (int i = 0; i < 8; ++i) {
      int f4 = tid + i * 256;          // 0..2047
      int row = f4 >> 5;               // 32 float4 per row
      int c4  = f4 & 31;
      float4 v = *(const float4*)(src + (size_t)row * srcStride + c4 * 4);
      ushort4 o;
      o.x = f2bf(v.x); o.y = f2bf(v.y); o.z = f2bf(v.z); o.w = f2bf(v.w);
      *(ushort4*)(dst + row * 132 + c4 * 4) = o;
    }
  };

  // ---- phase 0: stage obs + prev_belief ----
  stage(obs + (size_t)gRow0 * OBSD, OBSD, bufB);
  stage(pb  + (size_t)gRow0 * HD_,  HD_,  bufP);
  __syncthreads();

  { // A1: relu(obs @ W1^T + b1) -> t1
    f32x16 acc = gemm_acc<8>(bufB, 132, aRow, khalf, wsW1 + col64 * 128, zero16());
    epiLDS(acc, b1[col64], rowOff, col64, bufH1, 68, true);
  }
  { // Q1: pb @ Wp^T + bp -> q_in
    f32x16 acc = gemm_acc<8>(bufP, 132, aRow, khalf, wsWP + col64 * 128, zero16());
    epiLDS(acc, bp[col64], rowOff, col64, bufQ, 68, false);
  }
  __syncthreads();

  { // A2: relu(t1 @ W2^T + b2) -> h_obs
    f32x16 acc = gemm_acc<4>(bufH1, 68, aRow, khalf, wsW2 + col64 * 64, zero16());
    epiLDS(acc, b2[col64], rowOff, col64, bufHO, 68, true);
  }
  { // Q2: q_in @ Wq^T + bq -> q (into bufB cols 0..63; obs is dead)
    f32x16 acc = gemm_acc<4>(bufQ, 68, aRow, khalf, wsINP + col64 * 64, zero16());
    epiLDS(acc, inpb[col64], rowOff, col64, bufB, 132, false);
  }
  __syncthreads();

  // ---- attention (thread = one (row, head)) ----
  const int b  = tid >> 2;
  const int hh = tid & 3;
  float qreg[16];
#pragma unroll
  for (int d = 0; d < 16; ++d) qreg[d] = bf2f(bufB[b * 132 + hh * 16 + d]);
  float ctx[16];
#pragma unroll
  for (int d = 0; d < 16; ++d) ctx[d] = 0.f;
  float l = 0.f, parr[NT];
  __syncthreads();   // q consumed; bufB free for teammate tiles

  for (int t = 0; t < NT; ++t) {
    stage(th + (size_t)gRow0 * (NT * HD_) + t * HD_, NT * HD_, bufB);
    __syncthreads();
    { // KV1: th @ Wp^T + bp -> kv_in
      f32x16 acc = gemm_acc<8>(bufB, 132, aRow, khalf, wsWP + col64 * 128, zero16());
      epiLDS(acc, bp[col64], rowOff, col64, bufH1, 68, false);
    }
    __syncthreads();
    { // K2: kv_in @ Wk^T + bk -> k
      f32x16 acc = gemm_acc<4>(bufH1, 68, aRow, khalf, wsINP + (64 + col64) * 64, zero16());
      epiLDS(acc, inpb[64 + col64], rowOff, col64, bufQ, 68, false);
    }
    __syncthreads();
    { // scores: |s| < ~0.3 so exp without max-subtraction is exact
      float s = 0.f;
#pragma unroll
      for (int d = 0; d < 16; ++d) s += qreg[d] * bf2f(bufQ[b * 68 + hh * 16 + d]);
      float p = __expf(s * 0.25f);
      l += p; parr[t] = p;
    }
    __syncthreads();
    { // V2: kv_in @ Wv^T + bv -> v
      f32x16 acc = gemm_acc<4>(bufH1, 68, aRow, khalf, wsINP + (128 + col64) * 64, zero16());
      epiLDS(acc, inpb[128 + col64], rowOff, col64, bufQ, 68, false);
    }
    __syncthreads();
    { // PV accumulate (unnormalized)
      float p = parr[t];
#pragma unroll
      for (int d = 0; d < 16; ++d) ctx[d] += p * bf2f(bufQ[b * 68 + hh * 16 + d]);
    }
  }

  { // attn_weights (mean over heads) + normalized ctx -> bufH1
    float linv = 1.f / l;
#pragma unroll
    for (int t = 0; t < NT; ++t) {
      float a = parr[t] * linv;
      a += __shfl_xor(a, 1);
      a += __shfl_xor(a, 2);
      if (hh == 0) outAttn[(size_t)(gRow0 + b) * NT + t] = a * 0.25f;
    }
#pragma unroll
    for (int d = 0; d < 16; ++d) bufH1[b * 68 + hh * 16 + d] = f2bf(ctx[d] * linv);
  }
  __syncthreads();

  { // out_proj: ctx @ Wo^T + bo -> context
    f32x16 acc = gemm_acc<4>(bufH1, 68, aRow, khalf, wsOUTP + col64 * 64, zero16());
    epiLDS(acc, outpb[col64], rowOff, col64, bufQ, 68, false);
  }
  __syncthreads();

  // ---- GRU: gates via MFMA, epilogue fused in-register ----
  bf16x8 ax[8], apb[8];                       // x = [h_obs | context], pb
#pragma unroll
  for (int ks = 0; ks < 4; ++ks) ax[ks]     = ldsA(bufHO + aRow * 68 + ks * 16 + khalf);
#pragma unroll
  for (int ks = 0; ks < 4; ++ks) ax[4 + ks] = ldsA(bufQ  + aRow * 68 + ks * 16 + khalf);
#pragma unroll
  for (int ks = 0; ks < 8; ++ks) apb[ks]    = ldsA(bufP  + aRow * 132 + ks * 16 + khalf);

#pragma unroll
  for (int hj = 0; hj < 2; ++hj) {
    int jt = nh * 32 + hj * 64;
    int j  = jt + m;                          // gate output index 0..127
    const u16* wr = wsWIH + (0 * HD_ + j) * 128;
    const u16* wz = wsWIH + (1 * HD_ + j) * 128;
    const u16* wn = wsWIH + (2 * HD_ + j) * 128;
    const u16* vr = wsWHH + (0 * HD_ + j) * 128;
    const u16* vz = wsWHH + (1 * HD_ + j) * 128;
    const u16* vn = wsWHH + (2 * HD_ + j) * 128;
    f32x16 ar = zero16(), az = zero16(), ai = zero16(), ah = zero16();
#pragma unroll
    for (int ks = 0; ks < 8; ++ks) {          // 3 independent MFMA chains
      int ko = ks * 16 + khalf;
      ar = mfma(ax[ks], *(const bf16x8*)(wr + ko), ar);
      az = mfma(ax[ks], *(const bf16x8*)(wz + ko), az);
      ai = mfma(ax[ks], *(const bf16x8*)(wn + ko), ai);
    }
#pragma unroll
    for (int ks = 0; ks < 8; ++ks) {
      int ko = ks * 16 + khalf;
      ar = mfma(apb[ks], *(const bf16x8*)(vr + ko), ar);
      az = mfma(apb[ks], *(const bf16x8*)(vz + ko), az);
      ah = mfma(apb[ks], *(const bf16x8*)(vn + ko), ah);
    }
    float br_ = bih[j] + bhh[j];
    float bz_ = bih[HD_ + j] + bhh[HD_ + j];
    float bi_ = bih[2 * HD_ + j];
    float bh_ = bhh[2 * HD_ + j];
#pragma unroll
    for (int r = 0; r < 16; ++r) {
      int row = rowOff + (r & 3) + 8 * (r >> 2);
      float rr = sigf(ar[r] + br_);
      float zz = sigf(az[r] + bz_);
      float xn = ai[r] + bi_ + rr * (ah[r] + bh_);
      xn = fminf(fmaxf(xn, -15.f), 15.f);
      float tt = __expf(2.f * xn);
      float nn = (tt - 1.f) / (tt + 1.f);     // tanh
      float pv = bf2f(bufP[row * 132 + j]);
      float bel = (1.f - zz) * nn + zz * pv;
      outBel[(size_t)(gRow0 + row) * HD_ + j] = bel;
      bufB[row * 132 + j] = f2bf(bel);        // q is long dead
    }
  }
  __syncthreads();

  // ---- policy head (waves nh==0 only; N=16 < tile width 32) ----
  if (nh == 0) {
    int nclamp = (m < 16) ? m : 15;           // clamp B-row for lanes past N
    f32x16 acc = gemm_acc<8>(bufB, 132, aRow, khalf, wsPOL + nclamp * 128, zero16());
    if (m < 16) {
      float bv = bpol[m];
#pragma unroll
      for (int r = 0; r < 16; ++r) {
        int row = rowOff + (r & 3) + 8 * (r >> 2);
        outLog[(size_t)(gRow0 + row) * NA + m] = acc[r] + bv;
      }
    }
  }
}

extern "C" void kernel_launch(void* const* d_in, const int* in_sizes, int n_in,
                              void* d_out, int out_size, void* d_ws, size_t ws_size,
                              hipStream_t stream) {
  const float* obs   = (const float*)d_in[0];
  const float* pb    = (const float*)d_in[1];
  const float* th    = (const float*)d_in[2];
  const float* W1    = (const float*)d_in[3];
  const float* b1    = (const float*)d_in[4];
  const float* W2    = (const float*)d_in[5];
  const float* b2    = (const float*)d_in[6];
  const float* Wp    = (const float*)d_in[7];
  const float* bp    = (const float*)d_in[8];
  const float* inpw  = (const float*)d_in[9];
  const float* inpb  = (const float*)d_in[10];
  const float* outpw = (const float*)d_in[11];
  const float* outpb = (const float*)d_in[12];
  const float* wih   = (const float*)d_in[13];
  const float* whh   = (const float*)d_in[14];
  const float* bih   = (const float*)d_in[15];
  const float* bhh   = (const float*)d_in[16];
  const float* wpol  = (const float*)d_in[17];
  const float* bpol  = (const float*)d_in[18];

  u16* wsb = (u16*)d_ws;                      // 274 KB bf16 weights
  float* outLog  = (float*)d_out;
  float* outBel  = outLog + (size_t)NB * NA;
  float* outAttn = outBel + (size_t)NB * HD_;

  pack_weights<<<W_TOTAL / 256, 256, 0, stream>>>(W1, W2, Wp, inpw, outpw, wih, whh,
                                                  wpol, wsb);
  aerial_main<<<NB / 64, 256, 0, stream>>>(obs, pb, th, b1, b2, bp, inpb, outpb,
                                           bih, bhh, bpol, wsb, outLog, outBel, outAttn);
}